// Round 1
// baseline (179.260 us; speedup 1.0000x reference)
//
#include <hip/hip_runtime.h>
#include <hip/hip_bf16.h>

using short8  = __attribute__((ext_vector_type(8))) short;
using floatx4 = __attribute__((ext_vector_type(4))) float;

#define TEMP_INV 14.285714285714286f  // 1/0.07
#define DD 256
#define BM 128
#define BK 64
#define LDA 72  // BK + 8 bf16 pad -> fragment ds_read_b128 is 2-way (free)

// ---------------- kernel 1: L2 normalize rows, cast to bf16 ----------------
__global__ __launch_bounds__(256) void nrm_kernel(
    const float* __restrict__ anchor, const float* __restrict__ positive,
    __hip_bfloat16* __restrict__ abf, __hip_bfloat16* __restrict__ pbf) {
  const int wave = threadIdx.x >> 6;
  const int lane = threadIdx.x & 63;
  const int row  = blockIdx.x * 2 + (wave & 1);
  const float* src = (wave < 2) ? anchor : positive;
  __hip_bfloat16* dst = (wave < 2) ? abf : pbf;
  const float4 v = ((const float4*)(src + (size_t)row * DD))[lane];
  float ss = v.x * v.x + v.y * v.y + v.z * v.z + v.w * v.w;
#pragma unroll
  for (int m = 32; m >= 1; m >>= 1) ss += __shfl_xor(ss, m, 64);
  const float scale = 1.0f / fmaxf(sqrtf(ss), 1e-12f);
  union { ushort4 u; __hip_bfloat16 h[4]; } pk;
  pk.h[0] = __float2bfloat16(v.x * scale);
  pk.h[1] = __float2bfloat16(v.y * scale);
  pk.h[2] = __float2bfloat16(v.z * scale);
  pk.h[3] = __float2bfloat16(v.w * scale);
  *((ushort4*)(dst + (size_t)row * DD) + lane) = pk.u;
}

// ------ kernel 2: 128x128 MFMA sim tile + fused exp/max/diag epilogue ------
__global__ __launch_bounds__(256) void gemm_stats(
    const __hip_bfloat16* __restrict__ abf, const __hip_bfloat16* __restrict__ pbf,
    float* __restrict__ rsum, float* __restrict__ rmax,
    float* __restrict__ diag, int Btot) {
  __shared__ __align__(16) __hip_bfloat16 As[BM * LDA];
  __shared__ __align__(16) __hip_bfloat16 Bs[BM * LDA];
  __shared__ float red_sum[2][BM];
  __shared__ float red_max[2][BM];

  const int t = threadIdx.x;
  const int wave = t >> 6, lane = t & 63;
  const int wm = wave & 1, wn = wave >> 1;
  const int quad = lane >> 4, l16 = lane & 15;
  const int row0 = blockIdx.y * BM;
  const int col0 = blockIdx.x * BM;

  floatx4 acc[4][4];
#pragma unroll
  for (int a = 0; a < 4; ++a)
#pragma unroll
    for (int b = 0; b < 4; ++b) acc[a][b] = (floatx4){0.f, 0.f, 0.f, 0.f};

  for (int kc = 0; kc < DD; kc += BK) {
    __syncthreads();
    // stage A(128xBK) and B(128xBK): 8 rows x 8 chunks(16B) per wave pass
#pragma unroll
    for (int it = 0; it < 4; ++it) {
      const int idx = it * 256 + t;
      const int r = idx >> 3;
      const int c = idx & 7;
      const uint4 da = *(const uint4*)(abf + (size_t)(row0 + r) * DD + kc + c * 8);
      *(uint4*)(&As[r * LDA + c * 8]) = da;
      const uint4 db = *(const uint4*)(pbf + (size_t)(col0 + r) * DD + kc + c * 8);
      *(uint4*)(&Bs[r * LDA + c * 8]) = db;
    }
    __syncthreads();
#pragma unroll
    for (int h = 0; h < 2; ++h) {  // two K=32 halves per BK=64 chunk
      short8 af[4], bfr[4];
#pragma unroll
      for (int mi = 0; mi < 4; ++mi)
        af[mi] = *(const short8*)(&As[(wm * 64 + mi * 16 + l16) * LDA + h * 32 + quad * 8]);
#pragma unroll
      for (int ni = 0; ni < 4; ++ni)
        bfr[ni] = *(const short8*)(&Bs[(wn * 64 + ni * 16 + l16) * LDA + h * 32 + quad * 8]);
#pragma unroll
      for (int mi = 0; mi < 4; ++mi)
#pragma unroll
        for (int ni = 0; ni < 4; ++ni)
          acc[mi][ni] = __builtin_amdgcn_mfma_f32_16x16x32_bf16(af[mi], bfr[ni], acc[mi][ni], 0, 0, 0);
    }
  }

  // epilogue: C/D layout col=lane&15, row=quad*4+reg
#pragma unroll
  for (int mi = 0; mi < 4; ++mi) {
#pragma unroll
    for (int reg = 0; reg < 4; ++reg) {
      const int i = row0 + wm * 64 + mi * 16 + quad * 4 + reg;
      float se = 0.f, mx = -INFINITY;
#pragma unroll
      for (int ni = 0; ni < 4; ++ni) {
        const float s = acc[mi][ni][reg];
        const int j = col0 + wn * 64 + ni * 16 + l16;
        se += __expf(s * TEMP_INV);
        if (i == j) diag[i] = s;      // every diagonal elem hit exactly once
        else mx = fmaxf(mx, s);
      }
#pragma unroll
      for (int m = 1; m < 16; m <<= 1) {  // reduce across 16 cols (same quad)
        se += __shfl_xor(se, m, 64);
        mx = fmaxf(mx, __shfl_xor(mx, m, 64));
      }
      if (l16 == 0) {
        const int rb = wm * 64 + mi * 16 + quad * 4 + reg;
        red_sum[wn][rb] = se;
        red_max[wn][rb] = mx;
      }
    }
  }
  __syncthreads();
  if (t < BM) {
    rsum[(size_t)blockIdx.x * Btot + row0 + t] = red_sum[0][t] + red_sum[1][t];
    rmax[(size_t)blockIdx.x * Btot + row0 + t] = fmaxf(red_max[0][t], red_max[1][t]);
  }
}

// ---------------- kernel 3: reduce 64 column-tile partials per row ----------
__global__ __launch_bounds__(256) void row_loss_kernel(
    const float* __restrict__ rsum, const float* __restrict__ rmax,
    const float* __restrict__ diag, float* __restrict__ rloss, int Btot, int NT) {
  const int i = blockIdx.x * 256 + threadIdx.x;
  float s = 0.f, m = -INFINITY;
  for (int c = 0; c < NT; ++c) {
    s += rsum[(size_t)c * Btot + i];
    m = fmaxf(m, rmax[(size_t)c * Btot + i]);
  }
  // lse_i = log(sum_j exp(s_ij/T) + exp(maxneg_i/T)); loss_i = lse_i - s_ii/T
  rloss[i] = __logf(s + __expf(m * TEMP_INV)) - diag[i] * TEMP_INV;
}

// ---------------- kernel 4: mean over rows -> scalar --------------------
__global__ __launch_bounds__(256) void final_reduce(
    const float* __restrict__ rloss, float* __restrict__ out, int Btot) {
  float s = 0.f;
  for (int k = threadIdx.x; k < Btot; k += 256) s += rloss[k];
#pragma unroll
  for (int m = 32; m >= 1; m >>= 1) s += __shfl_xor(s, m, 64);
  __shared__ float red[4];
  if ((threadIdx.x & 63) == 0) red[threadIdx.x >> 6] = s;
  __syncthreads();
  if (threadIdx.x == 0) out[0] = (red[0] + red[1] + red[2] + red[3]) / (float)Btot;
}

extern "C" void kernel_launch(void* const* d_in, const int* in_sizes, int n_in,
                              void* d_out, int out_size, void* d_ws, size_t ws_size,
                              hipStream_t stream) {
  const float* anchor   = (const float*)d_in[0];
  const float* positive = (const float*)d_in[1];
  const int B  = in_sizes[0] / DD;  // 8192
  const int NT = B / BM;            // 64 column tiles
  const size_t BD = (size_t)B * DD;

  // ws layout: abf(4MB) | pbf(4MB) | rsum(NT*B f32) | rmax(NT*B f32) | diag(B) | rloss(B)
  __hip_bfloat16* abf = (__hip_bfloat16*)d_ws;
  __hip_bfloat16* pbf = abf + BD;
  float* rsum  = (float*)(pbf + BD);
  float* rmax  = rsum + (size_t)NT * B;
  float* diag  = rmax + (size_t)NT * B;
  float* rloss = diag + B;

  nrm_kernel<<<B / 2, 256, 0, stream>>>(anchor, positive, abf, pbf);
  dim3 g2(NT, NT);
  gemm_stats<<<g2, 256, 0, stream>>>(abf, pbf, rsum, rmax, diag, B);
  row_loss_kernel<<<B / 256, 256, 0, stream>>>(rsum, rmax, diag, rloss, B, NT);
  final_reduce<<<1, 256, 0, stream>>>(rloss, (float*)d_out, B);
}

// Round 2
// 153.733 us; speedup vs baseline: 1.1660x; 1.1660x over previous
//
#include <hip/hip_runtime.h>
#include <hip/hip_bf16.h>

using short8  = __attribute__((ext_vector_type(8))) short;
using floatx4 = __attribute__((ext_vector_type(4))) float;

#define TEMP_INV 14.285714285714286f  // 1/0.07
#define DD 256
#define BM 128
#define BK 64   // LDS row stride = 64 bf16 = 128 B = 8 granules of 16 B

typedef const __attribute__((address_space(1))) unsigned int* gptr_t;
typedef __attribute__((address_space(3))) unsigned int* lptr_t;

__device__ __forceinline__ void async_cp16(const void* g, void* l) {
  __builtin_amdgcn_global_load_lds((gptr_t)g, (lptr_t)l, 16, 0, 0);
}

// ---------------- kernel 1: L2 normalize rows, cast to bf16 ----------------
__global__ __launch_bounds__(256) void nrm_kernel(
    const float* __restrict__ anchor, const float* __restrict__ positive,
    __hip_bfloat16* __restrict__ abf, __hip_bfloat16* __restrict__ pbf) {
  const int wave = threadIdx.x >> 6;
  const int lane = threadIdx.x & 63;
  const int row  = blockIdx.x * 2 + (wave & 1);
  const float* src = (wave < 2) ? anchor : positive;
  __hip_bfloat16* dst = (wave < 2) ? abf : pbf;
  const float4 v = ((const float4*)(src + (size_t)row * DD))[lane];
  float ss = v.x * v.x + v.y * v.y + v.z * v.z + v.w * v.w;
#pragma unroll
  for (int m = 32; m >= 1; m >>= 1) ss += __shfl_xor(ss, m, 64);
  const float scale = 1.0f / fmaxf(sqrtf(ss), 1e-12f);
  union { ushort4 u; __hip_bfloat16 h[4]; } pk;
  pk.h[0] = __float2bfloat16(v.x * scale);
  pk.h[1] = __float2bfloat16(v.y * scale);
  pk.h[2] = __float2bfloat16(v.z * scale);
  pk.h[3] = __float2bfloat16(v.w * scale);
  *((ushort4*)(dst + (size_t)row * DD) + lane) = pk.u;
}

// ------ kernel 2: 128x128 MFMA sim tile + fused exp/max/diag epilogue ------
// Staging: global_load_lds width=16, XOR-swizzled granules (slot (r,c) holds
// global granule c^(r&7)), so fragment ds_read_b128 hits the uniform
// 8-lanes-per-bank-group floor with NO padding (global_load_lds-compatible).
__global__ __launch_bounds__(256) void gemm_stats(
    const __hip_bfloat16* __restrict__ abf, const __hip_bfloat16* __restrict__ pbf,
    float* __restrict__ rsum, float* __restrict__ rmax,
    float* __restrict__ diag, int Btot) {
  __shared__ __align__(16) __hip_bfloat16 As[BM * BK];
  __shared__ __align__(16) __hip_bfloat16 Bs[BM * BK];
  __shared__ float red_sum[2][BM];
  __shared__ float red_max[2][BM];

  const int t = threadIdx.x;
  const int wave = t >> 6, lane = t & 63;
  const int wm = wave & 1, wn = wave >> 1;
  const int quad = lane >> 4, l16 = lane & 15;
  const int row0 = blockIdx.y * BM;
  const int col0 = blockIdx.x * BM;

  // staging source decomposition: lane = r7*8 + c; source granule = c ^ r7
  const int r7   = lane >> 3;
  const int csrc = (lane & 7) ^ r7;

  floatx4 acc[4][4];
#pragma unroll
  for (int a = 0; a < 4; ++a)
#pragma unroll
    for (int b = 0; b < 4; ++b) acc[a][b] = (floatx4){0.f, 0.f, 0.f, 0.f};

#pragma unroll
  for (int kc = 0; kc < DD; kc += BK) {
    __syncthreads();
    // each wave: 4 issues for A + 4 for B; issue q covers 8 rows (1 KB LDS)
#pragma unroll
    for (int q = 0; q < 4; ++q) {
      const int r = wave * 32 + q * 8 + r7;
      async_cp16(abf + (size_t)(row0 + r) * DD + kc + csrc * 8,
                 &As[(wave * 32 + q * 8) * BK]);
      async_cp16(pbf + (size_t)(col0 + r) * DD + kc + csrc * 8,
                 &Bs[(wave * 32 + q * 8) * BK]);
    }
    __syncthreads();
#pragma unroll
    for (int h = 0; h < 2; ++h) {  // two K=32 halves per BK=64 chunk
      short8 af[4], bfr[4];
#pragma unroll
      for (int mi = 0; mi < 4; ++mi) {
        const int row = wm * 64 + mi * 16 + l16;
        af[mi] = *(const short8*)(&As[row * BK + (((h * 4 + quad) ^ (row & 7)) * 8)]);
      }
#pragma unroll
      for (int ni = 0; ni < 4; ++ni) {
        const int row = wn * 64 + ni * 16 + l16;
        bfr[ni] = *(const short8*)(&Bs[row * BK + (((h * 4 + quad) ^ (row & 7)) * 8)]);
      }
#pragma unroll
      for (int mi = 0; mi < 4; ++mi)
#pragma unroll
        for (int ni = 0; ni < 4; ++ni)
          acc[mi][ni] = __builtin_amdgcn_mfma_f32_16x16x32_bf16(af[mi], bfr[ni], acc[mi][ni], 0, 0, 0);
    }
  }

  // epilogue: C/D layout col=lane&15, row=quad*4+reg
#pragma unroll
  for (int mi = 0; mi < 4; ++mi) {
#pragma unroll
    for (int reg = 0; reg < 4; ++reg) {
      const int i = row0 + wm * 64 + mi * 16 + quad * 4 + reg;
      float se = 0.f, mx = -INFINITY;
#pragma unroll
      for (int ni = 0; ni < 4; ++ni) {
        const float s = acc[mi][ni][reg];
        const int j = col0 + wn * 64 + ni * 16 + l16;
        se += __expf(s * TEMP_INV);
        if (i == j) diag[i] = s;      // every diagonal elem hit exactly once
        else mx = fmaxf(mx, s);
      }
#pragma unroll
      for (int m = 1; m < 16; m <<= 1) {  // reduce across 16 cols (same quad)
        se += __shfl_xor(se, m, 64);
        mx = fmaxf(mx, __shfl_xor(mx, m, 64));
      }
      if (l16 == 0) {
        const int rb = wm * 64 + mi * 16 + quad * 4 + reg;
        red_sum[wn][rb] = se;
        red_max[wn][rb] = mx;
      }
    }
  }
  __syncthreads();
  if (t < BM) {
    rsum[(size_t)blockIdx.x * Btot + row0 + t] = red_sum[0][t] + red_sum[1][t];
    rmax[(size_t)blockIdx.x * Btot + row0 + t] = fmaxf(red_max[0][t], red_max[1][t]);
  }
}

// ---------------- kernel 3: reduce 64 column-tile partials per row ----------
__global__ __launch_bounds__(256) void row_loss_kernel(
    const float* __restrict__ rsum, const float* __restrict__ rmax,
    const float* __restrict__ diag, float* __restrict__ rloss, int Btot, int NT) {
  const int i = blockIdx.x * 256 + threadIdx.x;
  float s = 0.f, m = -INFINITY;
  for (int c = 0; c < NT; ++c) {
    s += rsum[(size_t)c * Btot + i];
    m = fmaxf(m, rmax[(size_t)c * Btot + i]);
  }
  // lse_i = log(sum_j exp(s_ij/T) + exp(maxneg_i/T)); loss_i = lse_i - s_ii/T
  rloss[i] = __logf(s + __expf(m * TEMP_INV)) - diag[i] * TEMP_INV;
}

// ---------------- kernel 4: mean over rows -> scalar --------------------
__global__ __launch_bounds__(256) void final_reduce(
    const float* __restrict__ rloss, float* __restrict__ out, int Btot) {
  float s = 0.f;
  for (int k = threadIdx.x; k < Btot; k += 256) s += rloss[k];
#pragma unroll
  for (int m = 32; m >= 1; m >>= 1) s += __shfl_xor(s, m, 64);
  __shared__ float red[4];
  if ((threadIdx.x & 63) == 0) red[threadIdx.x >> 6] = s;
  __syncthreads();
  if (threadIdx.x == 0) out[0] = (red[0] + red[1] + red[2] + red[3]) / (float)Btot;
}

extern "C" void kernel_launch(void* const* d_in, const int* in_sizes, int n_in,
                              void* d_out, int out_size, void* d_ws, size_t ws_size,
                              hipStream_t stream) {
  const float* anchor   = (const float*)d_in[0];
  const float* positive = (const float*)d_in[1];
  const int B  = in_sizes[0] / DD;  // 8192
  const int NT = B / BM;            // 64 column tiles
  const size_t BD = (size_t)B * DD;

  // ws layout: abf(4MB) | pbf(4MB) | rsum(NT*B f32) | rmax(NT*B f32) | diag(B) | rloss(B)
  __hip_bfloat16* abf = (__hip_bfloat16*)d_ws;
  __hip_bfloat16* pbf = abf + BD;
  float* rsum  = (float*)(pbf + BD);
  float* rmax  = rsum + (size_t)NT * B;
  float* diag  = rmax + (size_t)NT * B;
  float* rloss = diag + B;

  nrm_kernel<<<B / 2, 256, 0, stream>>>(anchor, positive, abf, pbf);
  dim3 g2(NT, NT);
  gemm_stats<<<g2, 256, 0, stream>>>(abf, pbf, rsum, rmax, diag, B);
  row_loss_kernel<<<B / 256, 256, 0, stream>>>(rsum, rmax, diag, rloss, B, NT);
  final_reduce<<<1, 256, 0, stream>>>(rloss, (float*)d_out, B);
}

// Round 3
// 129.906 us; speedup vs baseline: 1.3799x; 1.1834x over previous
//
#include <hip/hip_runtime.h>
#include <hip/hip_bf16.h>

using short8  = __attribute__((ext_vector_type(8))) short;
using floatx4 = __attribute__((ext_vector_type(4))) float;

#define TEMP_INV 14.285714285714286f  // 1/0.07
#define DD 256
#define BM 128
#define BK 64   // LDS row stride = 64 bf16 = 128 B = 8 granules of 16 B
#define NCT 4   // column tiles per block

typedef const __attribute__((address_space(1))) unsigned int* gptr_t;
typedef __attribute__((address_space(3))) unsigned int* lptr_t;

__device__ __forceinline__ void async_cp16(const void* g, void* l) {
  __builtin_amdgcn_global_load_lds((gptr_t)g, (lptr_t)l, 16, 0, 0);
}

// ---------------- kernel 1: L2 normalize rows, cast to bf16 ----------------
__global__ __launch_bounds__(256) void nrm_kernel(
    const float* __restrict__ anchor, const float* __restrict__ positive,
    __hip_bfloat16* __restrict__ abf, __hip_bfloat16* __restrict__ pbf) {
  const int wave = threadIdx.x >> 6;
  const int lane = threadIdx.x & 63;
  const int row  = blockIdx.x * 2 + (wave & 1);
  const float* src = (wave < 2) ? anchor : positive;
  __hip_bfloat16* dst = (wave < 2) ? abf : pbf;
  const float4 v = ((const float4*)(src + (size_t)row * DD))[lane];
  float ss = v.x * v.x + v.y * v.y + v.z * v.z + v.w * v.w;
#pragma unroll
  for (int m = 32; m >= 1; m >>= 1) ss += __shfl_xor(ss, m, 64);
  const float scale = 1.0f / fmaxf(sqrtf(ss), 1e-12f);
  union { ushort4 u; __hip_bfloat16 h[4]; } pk;
  pk.h[0] = __float2bfloat16(v.x * scale);
  pk.h[1] = __float2bfloat16(v.y * scale);
  pk.h[2] = __float2bfloat16(v.z * scale);
  pk.h[3] = __float2bfloat16(v.w * scale);
  *((ushort4*)(dst + (size_t)row * DD) + lane) = pk.u;
}

// ------ kernel 2: one 128-row band x 4 column tiles, fused stats ------
// Staging: global_load_lds width=16, XOR-swizzled granules (slot (r,c) holds
// global granule c^(r&7)) -> conflict-free ds_read_b128 without padding.
// Running (sum-exp, max) kept in registers across the 4 column tiles; the
// 16-lane cross-reduction runs ONCE per block (was once per tile).
__global__ __launch_bounds__(256) void gemm_stats(
    const __hip_bfloat16* __restrict__ abf, const __hip_bfloat16* __restrict__ pbf,
    float* __restrict__ rsum, float* __restrict__ rmax,
    float* __restrict__ diag, int Btot) {
  __shared__ __align__(16) __hip_bfloat16 As[BM * BK];
  __shared__ __align__(16) __hip_bfloat16 Bs[BM * BK];
  __shared__ float red_sum[2][BM];
  __shared__ float red_max[2][BM];

  const int t = threadIdx.x;
  const int wave = t >> 6, lane = t & 63;
  const int wm = wave & 1, wn = wave >> 1;
  const int quad = lane >> 4, l16 = lane & 15;
  const int row0    = blockIdx.y * BM;
  const int colbase = blockIdx.x * (NCT * BM);

  // staging source decomposition: lane = r7*8 + c; source granule = c ^ r7
  const int r7   = lane >> 3;
  const int csrc = (lane & 7) ^ r7;

  float se_run[4][4], mx_run[4][4];
#pragma unroll
  for (int a = 0; a < 4; ++a)
#pragma unroll
    for (int b = 0; b < 4; ++b) { se_run[a][b] = 0.f; mx_run[a][b] = -INFINITY; }

  for (int ct = 0; ct < NCT; ++ct) {
    const int col0 = colbase + ct * BM;
    floatx4 acc[4][4];
#pragma unroll
    for (int a = 0; a < 4; ++a)
#pragma unroll
      for (int b = 0; b < 4; ++b) acc[a][b] = (floatx4){0.f, 0.f, 0.f, 0.f};

#pragma unroll
    for (int kc = 0; kc < DD; kc += BK) {
      __syncthreads();
#pragma unroll
      for (int q = 0; q < 4; ++q) {
        const int r = wave * 32 + q * 8 + r7;
        async_cp16(abf + (size_t)(row0 + r) * DD + kc + csrc * 8,
                   &As[(wave * 32 + q * 8) * BK]);
        async_cp16(pbf + (size_t)(col0 + r) * DD + kc + csrc * 8,
                   &Bs[(wave * 32 + q * 8) * BK]);
      }
      __syncthreads();
#pragma unroll
      for (int h = 0; h < 2; ++h) {  // two K=32 halves per BK=64 chunk
        short8 af[4], bfr[4];
#pragma unroll
        for (int mi = 0; mi < 4; ++mi) {
          const int row = wm * 64 + mi * 16 + l16;
          af[mi] = *(const short8*)(&As[row * BK + (((h * 4 + quad) ^ (row & 7)) * 8)]);
        }
#pragma unroll
        for (int ni = 0; ni < 4; ++ni) {
          const int row = wn * 64 + ni * 16 + l16;
          bfr[ni] = *(const short8*)(&Bs[row * BK + (((h * 4 + quad) ^ (row & 7)) * 8)]);
        }
#pragma unroll
        for (int mi = 0; mi < 4; ++mi)
#pragma unroll
          for (int ni = 0; ni < 4; ++ni)
            acc[mi][ni] = __builtin_amdgcn_mfma_f32_16x16x32_bf16(af[mi], bfr[ni], acc[mi][ni], 0, 0, 0);
      }
    }

    // per-tile accumulate into running stats (no cross-lane work here)
    // C/D layout: col=lane&15, row=quad*4+reg
#pragma unroll
    for (int mi = 0; mi < 4; ++mi) {
#pragma unroll
      for (int reg = 0; reg < 4; ++reg) {
        const int i = row0 + wm * 64 + mi * 16 + quad * 4 + reg;
#pragma unroll
        for (int ni = 0; ni < 4; ++ni) {
          const float s = acc[mi][ni][reg];
          const int j = col0 + wn * 64 + ni * 16 + l16;
          se_run[mi][reg] += __expf(s * TEMP_INV);
          if (i == j) diag[i] = s;      // every diagonal elem hit exactly once
          else mx_run[mi][reg] = fmaxf(mx_run[mi][reg], s);
        }
      }
    }
  }

  // once-per-block 16-lane reduction
#pragma unroll
  for (int mi = 0; mi < 4; ++mi) {
#pragma unroll
    for (int reg = 0; reg < 4; ++reg) {
      float se = se_run[mi][reg], mx = mx_run[mi][reg];
#pragma unroll
      for (int m = 1; m < 16; m <<= 1) {
        se += __shfl_xor(se, m, 64);
        mx = fmaxf(mx, __shfl_xor(mx, m, 64));
      }
      if (l16 == 0) {
        const int rb = wm * 64 + mi * 16 + quad * 4 + reg;
        red_sum[wn][rb] = se;
        red_max[wn][rb] = mx;
      }
    }
  }
  __syncthreads();
  if (t < BM) {
    rsum[(size_t)blockIdx.x * Btot + row0 + t] = red_sum[0][t] + red_sum[1][t];
    rmax[(size_t)blockIdx.x * Btot + row0 + t] = fmaxf(red_max[0][t], red_max[1][t]);
  }
}

// ---------------- kernel 3: reduce column-group partials per row ----------
__global__ __launch_bounds__(256) void row_loss_kernel(
    const float* __restrict__ rsum, const float* __restrict__ rmax,
    const float* __restrict__ diag, float* __restrict__ rloss, int Btot, int NG) {
  const int i = blockIdx.x * 256 + threadIdx.x;
  float s = 0.f, m = -INFINITY;
  for (int c = 0; c < NG; ++c) {
    s += rsum[(size_t)c * Btot + i];
    m = fmaxf(m, rmax[(size_t)c * Btot + i]);
  }
  // lse_i = log(sum_j exp(s_ij/T) + exp(maxneg_i/T)); loss_i = lse_i - s_ii/T
  rloss[i] = __logf(s + __expf(m * TEMP_INV)) - diag[i] * TEMP_INV;
}

// ---------------- kernel 4: mean over rows -> scalar --------------------
__global__ __launch_bounds__(256) void final_reduce(
    const float* __restrict__ rloss, float* __restrict__ out, int Btot) {
  float s = 0.f;
  for (int k = threadIdx.x; k < Btot; k += 256) s += rloss[k];
#pragma unroll
  for (int m = 32; m >= 1; m >>= 1) s += __shfl_xor(s, m, 64);
  __shared__ float red[4];
  if ((threadIdx.x & 63) == 0) red[threadIdx.x >> 6] = s;
  __syncthreads();
  if (threadIdx.x == 0) out[0] = (red[0] + red[1] + red[2] + red[3]) / (float)Btot;
}

extern "C" void kernel_launch(void* const* d_in, const int* in_sizes, int n_in,
                              void* d_out, int out_size, void* d_ws, size_t ws_size,
                              hipStream_t stream) {
  const float* anchor   = (const float*)d_in[0];
  const float* positive = (const float*)d_in[1];
  const int B  = in_sizes[0] / DD;     // 8192
  const int NG = B / (BM * NCT);       // 16 column groups
  const size_t BD = (size_t)B * DD;

  // ws layout: abf(4MB) | pbf(4MB) | rsum(NG*B f32) | rmax(NG*B f32) | diag(B) | rloss(B)
  __hip_bfloat16* abf = (__hip_bfloat16*)d_ws;
  __hip_bfloat16* pbf = abf + BD;
  float* rsum  = (float*)(pbf + BD);
  float* rmax  = rsum + (size_t)NG * B;
  float* diag  = rmax + (size_t)NG * B;
  float* rloss = diag + B;

  nrm_kernel<<<B / 2, 256, 0, stream>>>(anchor, positive, abf, pbf);
  dim3 g2(NG, B / BM);
  gemm_stats<<<g2, 256, 0, stream>>>(abf, pbf, rsum, rmax, diag, B);
  row_loss_kernel<<<B / 256, 256, 0, stream>>>(rsum, rmax, diag, rloss, B, NG);
  final_reduce<<<1, 256, 0, stream>>>(rloss, (float*)d_out, B);
}